// Round 5
// baseline (130.408 us; speedup 1.0000x reference)
//
#include <hip/hip_runtime.h>

// DCNv2 forward = prep (weight repack + NHWC fp16 transpose) + FUSED
// im2col+GEMM. R17: register-direct B-frag, zero LDS round-trip.
//   Gather lane = (quad,l16): pixel l16, channel octets {quad, quad+4}
//   (2 x 16B per corner) -> packed-fp16 bilinear combine produces the MFMA
//   B-frag IN THE RIGHT LANES. No Bt LDS at all (13.8 KB LDS = coefs only).
//   Pipeline pinned with sched_barrier(0): iter t = COMBINE(t) ->
//   ISSUE(t+2) -> fence -> 8x MFMA. R13/R16 proved hipcc sinks unpinned
//   loads (VGPR 44/52, serial); the fence + launch_bounds(256,3) forces
//   the 2-deep stage to live in registers. A repacked so each afr load is
//   one contiguous 1KB wave transaction.
#define N_    4
#define C_    64
#define H_    128
#define W_    128
#define KW_   3
#define K_    9
#define COUT_ 64
#define HW_   (H_ * W_)     // 16384
#define NPIX  (N_ * HW_)    // 65536
#define KK_   (C_ * K_)     // 576

typedef _Float16 h4 __attribute__((ext_vector_type(4)));
typedef _Float16 h8 __attribute__((ext_vector_type(8)));   // 16B, 4 VGPRs
typedef float v4f __attribute__((ext_vector_type(4)));     // MFMA C/D
typedef int   v4i __attribute__((ext_vector_type(4)));

// ---------------------------------------------------------------------------
// prep: one dispatch doing both prologue jobs.
//   blocks 0..1023  : NCHW fp32 -> NHWC fp16 transpose xh[n][hw][c]
//   blocks 1024..1167: wA4 repack: wA4[(t*8+kc*4+mh)*512 + l16*32 + ch]
//                      = fp16(w[mh*16+l16][kc*32+ch][t])
// ---------------------------------------------------------------------------
__global__ __launch_bounds__(256) void prep(
    const float* __restrict__ x, _Float16* __restrict__ xh,
    const float* __restrict__ w, _Float16* __restrict__ wA4)
{
    if (blockIdx.x < 1024) {
        const int n   = blockIdx.x >> 8;            // 4 images x 256 hw-tiles
        const int hw0 = (blockIdx.x & 255) * 64;

        __shared__ float tile[64][65];              // [hw][c], pad
        const float* xb = x + n * (C_ * HW_);
#pragma unroll
        for (int i = 0; i < 4; ++i) {
            const int idx = i * 256 + threadIdx.x;  // 0..1023
            const int q   = idx & 15;               // hw quad 0..15
            const int c   = idx >> 4;               // 0..63
            const v4f v = *(const v4f*)&xb[c * HW_ + hw0 + 4 * q];
            tile[4 * q + 0][c] = v.x;
            tile[4 * q + 1][c] = v.y;
            tile[4 * q + 2][c] = v.z;
            tile[4 * q + 3][c] = v.w;
        }
        __syncthreads();
        _Float16* xo = xh + ((size_t)n * HW_ + hw0) * 64;
#pragma unroll
        for (int i = 0; i < 4; ++i) {
            const int idx = i * 256 + threadIdx.x;
            const int c4  = idx & 15;               // c quad 0..15
            const int hr  = idx >> 4;               // 0..63
            h4 v;
            v.x = (_Float16)tile[hr][4 * c4 + 0];
            v.y = (_Float16)tile[hr][4 * c4 + 1];
            v.z = (_Float16)tile[hr][4 * c4 + 2];
            v.w = (_Float16)tile[hr][4 * c4 + 3];
            *(h4*)&xo[hr * 64 + 4 * c4] = v;        // 8B store, coalesced
        }
    } else {
        const int tid = (blockIdx.x - 1024) * 256 + threadIdx.x;  // 0..36863
        if (tid < COUT_ * KK_) {
            const int blk = tid >> 9;               // t*8 + kc*4 + mh (0..71)
            const int r   = tid & 511;
            const int l16 = r >> 5;
            const int ch  = r & 31;
            const int t   = blk >> 3;
            const int kc  = (blk >> 2) & 1;
            const int mh  = blk & 3;
            const int o   = mh * 16 + l16;
            const int c   = kc * 32 + ch;
            wA4[tid] = (_Float16)w[o * (C_ * K_) + c * K_ + t];
        }
    }
}

// ---------------------------------------------------------------------------
// Fused im2col+GEMM. Block = 256 thr / 4 waves; wave owns 16 px x 64 cout,
// fully independent (no block barrier in the loop). Lane (quad,l16):
//   gathers pixel l16's octets quad (kc0) and quad+4 (kc1) per corner ->
//   4 corner addrs x 2 h8 loads; combine = 32 v_pk_fma_f16 -> bfr[2];
//   8 MFMA 16x16x32_f16 (afr: contiguous 1KB wave loads from wA4).
// Pipeline: COMBINE(t) ; ISSUE(t+2) ; sched_barrier(0) ; MFMA(t).
// ---------------------------------------------------------------------------
__global__ __launch_bounds__(256, 3) void dcn_fused(
    const _Float16* __restrict__ xh,   // (N, HW, C) fp16
    const float* __restrict__ offset,  // (N, 2*K, H, W)
    const float* __restrict__ mask,    // (N, K, H, W)
    const _Float16* __restrict__ wA4,  // repacked A, see prep
    const float* __restrict__ bias,
    float* __restrict__ out)           // (N, Cout, H, W)
{
    const int tid  = threadIdx.x;
    const int lane = tid & 63;
    const int wv   = tid >> 6;
    const int quad = lane >> 4;        // k-octet selector (gather + MFMA)
    const int l16  = lane & 15;        // pixel (gather + MFMA col)

    const int lb  = (blockIdx.x & 7) * 128 + (blockIdx.x >> 3);  // XCD swizzle
    const int pxb = lb * 64;                     // 64 | HW_: one image per block
    const int n   = pxb >> 14;
    const int hwb = pxb & (HW_ - 1);
    const int hww = hwb + wv * 16;               // wave's hw base

    __shared__ h4  cwh[4][144];                  // 4.6 KB  [wv][p*9+t]
    __shared__ v4i ci[4][144];                   // 9.2 KB  [wv][p*9+t]

    // ---- wave-local coef phase: this wave's 16 px x 9 taps = 144 entries ----
#pragma unroll
    for (int r = 0; r < 3; ++r) {
        const int e = r * 64 + lane;
        if (e < 144) {
            const int p  = e / 9;                // magic-mul
            const int t  = e - p * 9;
            const int hw = hww + p;
            const int ho = hw >> 7;
            const int wo = hw & (W_ - 1);
            const int ky = t / KW_;
            const int kx = t - ky * KW_;

            const float offy = offset[n * (2 * K_ * HW_) + (2 * t + 0) * HW_ + hw];
            const float offx = offset[n * (2 * K_ * HW_) + (2 * t + 1) * HW_ + hw];
            const float mval = mask[n * (K_ * HW_) + t * HW_ + hw];

            const float py = (float)(ho - 1 + ky) + offy;   // stride=1,pad=1,dil=1
            const float qx = (float)(wo - 1 + kx) + offx;
            const float y0f = floorf(py), x0f = floorf(qx);
            const float ly = py - y0f, lx = qx - x0f;
            const int y0 = (int)y0f, x0 = (int)x0f;
            const int y1 = y0 + 1,   x1 = x0 + 1;
            const bool vy0 = (y0 >= 0) & (y0 < H_);
            const bool vy1 = (y1 >= 0) & (y1 < H_);
            const bool vx0 = (x0 >= 0) & (x0 < W_);
            const bool vx1 = (x1 >= 0) & (x1 < W_);
            const int cy0 = min(max(y0, 0), H_ - 1);
            const int cy1 = min(max(y1, 0), H_ - 1);
            const int cx0 = min(max(x0, 0), W_ - 1);
            const int cx1 = min(max(x1, 0), W_ - 1);

            h4 q;
            q.x = (_Float16)((1.f - ly) * (1.f - lx) * mval * ((vy0 && vx0) ? 1.f : 0.f));
            q.y = (_Float16)((1.f - ly) * lx         * mval * ((vy0 && vx1) ? 1.f : 0.f));
            q.z = (_Float16)(ly         * (1.f - lx) * mval * ((vy1 && vx0) ? 1.f : 0.f));
            q.w = (_Float16)(ly         * lx         * mval * ((vy1 && vx1) ? 1.f : 0.f));
            cwh[wv][e] = q;
            v4i ii;
            ii.x = cy0 * W_ + cx0;
            ii.y = cy0 * W_ + cx1;
            ii.z = cy1 * W_ + cx0;
            ii.w = cy1 * W_ + cx1;
            ci[wv][e] = ii;
        }
    }
    __syncthreads();

    // gather base: this lane's pixel = l16, octet pair {quad, quad+4}
    const _Float16* xbq = xh + ((size_t)n * HW_) * 64 + quad * 8;

    v4f acc[4];                                  // mh: cout block mh*16
#pragma unroll
    for (int mh = 0; mh < 4; ++mh) acc[mh] = (v4f){0.f, 0.f, 0.f, 0.f};

    // register stages: [corner 0..3][kc 0/1], h8 each = 32 VGPR/stage
    h8 LA[4][2], LB[4][2];

    // issue tap t's 8 loads (4 corners x 2 kc) into stage R
#define ISSUE(t, R)                                                         \
    {                                                                       \
        const v4i o = ci[wv][l16 * 9 + (t)];                                \
        const _Float16* a0 = xbq + (size_t)o.x * 64;                        \
        const _Float16* a1 = xbq + (size_t)o.y * 64;                        \
        const _Float16* a2 = xbq + (size_t)o.z * 64;                        \
        const _Float16* a3 = xbq + (size_t)o.w * 64;                        \
        R[0][0] = *(const h8*)(a0);  R[0][1] = *(const h8*)(a0 + 32);       \
        R[1][0] = *(const h8*)(a1);  R[1][1] = *(const h8*)(a1 + 32);       \
        R[2][0] = *(const h8*)(a2);  R[2][1] = *(const h8*)(a2 + 32);       \
        R[3][0] = *(const h8*)(a3);  R[3][1] = *(const h8*)(a3 + 32);       \
    }

    // combine stage R for tap t into B-frags (in-lane, no LDS)
#define COMBINE(t, R, bfr0, bfr1)                                           \
    {                                                                       \
        const h4 f = cwh[wv][l16 * 9 + (t)];                                \
        const h8 F0 = {f.x, f.x, f.x, f.x, f.x, f.x, f.x, f.x};             \
        const h8 F1 = {f.y, f.y, f.y, f.y, f.y, f.y, f.y, f.y};             \
        const h8 F2 = {f.z, f.z, f.z, f.z, f.z, f.z, f.z, f.z};             \
        const h8 F3 = {f.w, f.w, f.w, f.w, f.w, f.w, f.w, f.w};             \
        bfr0 = F0 * R[0][0];                                                \
        bfr0 = __builtin_elementwise_fma(F1, R[1][0], bfr0);                \
        bfr0 = __builtin_elementwise_fma(F2, R[2][0], bfr0);                \
        bfr0 = __builtin_elementwise_fma(F3, R[3][0], bfr0);                \
        bfr1 = F0 * R[0][1];                                                \
        bfr1 = __builtin_elementwise_fma(F1, R[1][1], bfr1);                \
        bfr1 = __builtin_elementwise_fma(F2, R[2][1], bfr1);                \
        bfr1 = __builtin_elementwise_fma(F3, R[3][1], bfr1);                \
    }

    // ---- prologue: fill the 2-deep pipeline ----
    ISSUE(0, LA)
    ISSUE(1, LB)
    __builtin_amdgcn_sched_barrier(0);

    // A-frag base for this lane (per (t,kc,mh) block = 512 fp16)
    const _Float16* ab = wA4 + l16 * 32 + quad * 8;

    // ---- main loop: 9 taps, no block barriers, fence-pinned pipeline ----
#pragma unroll
    for (int t = 0; t < K_; ++t) {
        h8 bfr0, bfr1;
        if ((t & 1) == 0) {
            COMBINE(t, LA, bfr0, bfr1)
            if (t + 2 < K_) ISSUE(t + 2, LA)
        } else {
            COMBINE(t, LB, bfr0, bfr1)
            if (t + 2 < K_) ISSUE(t + 2, LB)
        }
        __builtin_amdgcn_sched_barrier(0);   // pin loads above the MFMA block

        __builtin_amdgcn_s_setprio(1);
#pragma unroll
        for (int kc = 0; kc < 2; ++kc) {
            const h8 bb = kc ? bfr1 : bfr0;
#pragma unroll
            for (int mh = 0; mh < 4; ++mh) {
                const h8 afr = *(const h8*)(ab + (size_t)(t * 8 + kc * 4 + mh) * 512);
                acc[mh] = __builtin_amdgcn_mfma_f32_16x16x32_f16(
                    afr, bb, acc[mh], 0, 0, 0);
            }
        }
        __builtin_amdgcn_s_setprio(0);
    }
#undef ISSUE
#undef COMBINE

    // D layout (R4-verified, dtype-independent): col = l16 (px), row = quad*4+r
    float* outb = out + n * (COUT_ * HW_) + hwb + wv * 16 + l16;
#pragma unroll
    for (int mh = 0; mh < 4; ++mh)
#pragma unroll
        for (int r = 0; r < 4; ++r) {
            const int m = mh * 16 + quad * 4 + r;
            outb[m * HW_] = acc[mh][r] + bias[m];
        }
}

// ---------------------------------------------------------------------------
// Fallback (ws too small): R3-style direct fp32 kernel, no ws needed.
// ---------------------------------------------------------------------------
__global__ __launch_bounds__(256) void dcn_fallback(
    const float* __restrict__ x, const float* __restrict__ offset,
    const float* __restrict__ mask, const float* __restrict__ wptr,
    const float* __restrict__ bias, float* __restrict__ out)
{
    const int pix = blockIdx.x * 256 + threadIdx.x;
    const int n = pix >> 14, hw = pix & (HW_ - 1);
    const int ho = hw >> 7,  wo = hw & (W_ - 1);
    float acc[COUT_];
#pragma unroll
    for (int o = 0; o < COUT_; ++o) acc[o] = bias[o];
    const float* xn   = x + n * (C_ * HW_);
    const float* offn = offset + n * (2 * K_ * HW_) + hw;
    const float* mn   = mask + n * (K_ * HW_) + hw;
    for (int ct = 0; ct < C_; ct += 8) {
        for (int k = 0; k < K_; ++k) {
            const int ky = k / KW_, kx = k - ky * KW_;
            const float off_y = offn[(2 * k + 0) * HW_];
            const float off_x = offn[(2 * k + 1) * HW_];
            const float m = mn[k * HW_];
            const float py = (float)(ho - 1 + ky) + off_y;
            const float px = (float)(wo - 1 + kx) + off_x;
            const float y0f = floorf(py), x0f = floorf(px);
            const float ly = py - y0f, lx = px - x0f;
            const int y0 = (int)y0f, x0 = (int)x0f, y1 = y0 + 1, x1 = x0 + 1;
            const bool vy0 = (y0 >= 0) & (y0 < H_), vy1 = (y1 >= 0) & (y1 < H_);
            const bool vx0 = (x0 >= 0) & (x0 < W_), vx1 = (x1 >= 0) & (x1 < W_);
            const int cy0 = min(max(y0, 0), H_ - 1), cy1 = min(max(y1, 0), H_ - 1);
            const int cx0 = min(max(x0, 0), W_ - 1), cx1 = min(max(x1, 0), W_ - 1);
            const int i00 = cy0 * W_ + cx0, i01 = cy0 * W_ + cx1;
            const int i10 = cy1 * W_ + cx0, i11 = cy1 * W_ + cx1;
            const float f00 = (1.f - ly) * (1.f - lx) * m * ((vy0 && vx0) ? 1.f : 0.f);
            const float f01 = (1.f - ly) * lx * m * ((vy0 && vx1) ? 1.f : 0.f);
            const float f10 = ly * (1.f - lx) * m * ((vy1 && vx0) ? 1.f : 0.f);
            const float f11 = ly * lx * m * ((vy1 && vx1) ? 1.f : 0.f);
            for (int cc = 0; cc < 8; ++cc) {
                const int c = ct + cc;
                const float* xc = xn + c * HW_;
                const float val = fmaf(f00, xc[i00], fmaf(f01, xc[i01],
                                  fmaf(f10, xc[i10], f11 * xc[i11])));
#pragma unroll
                for (int o = 0; o < COUT_; ++o)
                    acc[o] = fmaf(wptr[o * (C_ * K_) + c * K_ + k], val, acc[o]);
            }
        }
    }
    float* outp = out + n * (COUT_ * HW_) + hw;
#pragma unroll
    for (int o = 0; o < COUT_; ++o) outp[o * HW_] = acc[o];
}

extern "C" void kernel_launch(void* const* d_in, const int* in_sizes, int n_in,
                              void* d_out, int out_size, void* d_ws, size_t ws_size,
                              hipStream_t stream) {
    const float* x      = (const float*)d_in[0];
    const float* offset = (const float*)d_in[1];
    const float* mask   = (const float*)d_in[2];
    const float* weight = (const float*)d_in[3];
    const float* bias   = (const float*)d_in[4];
    float* out = (float*)d_out;

    const size_t xh_bytes = (size_t)NPIX * C_ * sizeof(_Float16);  // 8.4 MB
    const size_t wA_bytes = (size_t)COUT_ * KK_ * sizeof(_Float16);// 73.7 KB

    if (ws_size >= xh_bytes + wA_bytes) {
        _Float16* xh  = (_Float16*)d_ws;
        _Float16* wA4 = (_Float16*)((char*)d_ws + xh_bytes);
        prep<<<1024 + 144, 256, 0, stream>>>(x, xh, weight, wA4);
        dcn_fused<<<NPIX / 64, 256, 0, stream>>>(xh, offset, mask, wA4, bias, out);
    } else {
        dcn_fallback<<<NPIX / 256, 256, 0, stream>>>(x, offset, mask, weight, bias, out);
    }
}

// Round 7
// 102.242 us; speedup vs baseline: 1.2755x; 1.2755x over previous
//
#include <hip/hip_runtime.h>

// DCNv2 forward = prep (weight repack + NHWC fp16 transpose) + FUSED
// im2col+GEMM. R19: R15's verified dataflow (fp16 gather, 2-deep register
// pipeline, Bt double buffer, barrier per tap) with the barrier DRAIN
// removed: raw s_barrier + lgkmcnt(0) only (T3/T4 counted-vmcnt pattern,
// m201-verified). __syncthreads' vmcnt(0) was killing the prefetch every
// tap; now ISSUE(t+2) stays in flight a full iteration. VMEM order per
// iter = [A(t) 4][ISSUE(t+2) 8] so the compiler's A-frag wait is
// vmcnt(8): retires ISSUE(t+1) (1 iter old) and leaves ISSUE(t+2)
// flying. A uses R17's verified contiguous wA4 repack.
// (R18 DMA design failed correctness; reverted per rigor discipline.)
#define N_    4
#define C_    64
#define H_    128
#define W_    128
#define KW_   3
#define K_    9
#define COUT_ 64
#define HW_   (H_ * W_)     // 16384
#define NPIX  (N_ * HW_)    // 65536
#define KK_   (C_ * K_)     // 576

typedef _Float16 h4 __attribute__((ext_vector_type(4)));
typedef _Float16 h8 __attribute__((ext_vector_type(8)));   // 16B, 4 VGPRs
typedef float v4f __attribute__((ext_vector_type(4)));     // MFMA C/D
typedef int   v4i __attribute__((ext_vector_type(4)));

// ---------------------------------------------------------------------------
// prep: one dispatch doing both prologue jobs.
//   blocks 0..1023  : NCHW fp32 -> NHWC fp16 transpose xh[n][hw][c]
//   blocks 1024..1167: wA4 repack (R17-verified):
//     wA4[(t*8+kc*4+mh)*512 + l16*32 + ch] = fp16(w[mh*16+l16][kc*32+ch][t])
// ---------------------------------------------------------------------------
__global__ __launch_bounds__(256) void prep(
    const float* __restrict__ x, _Float16* __restrict__ xh,
    const float* __restrict__ w, _Float16* __restrict__ wA4)
{
    if (blockIdx.x < 1024) {
        const int n   = blockIdx.x >> 8;            // 4 images x 256 hw-tiles
        const int hw0 = (blockIdx.x & 255) * 64;

        __shared__ float tile[64][65];              // [hw][c], pad
        const float* xb = x + n * (C_ * HW_);
#pragma unroll
        for (int i = 0; i < 4; ++i) {
            const int idx = i * 256 + threadIdx.x;  // 0..1023
            const int q   = idx & 15;               // hw quad 0..15
            const int c   = idx >> 4;               // 0..63
            const v4f v = *(const v4f*)&xb[c * HW_ + hw0 + 4 * q];
            tile[4 * q + 0][c] = v.x;
            tile[4 * q + 1][c] = v.y;
            tile[4 * q + 2][c] = v.z;
            tile[4 * q + 3][c] = v.w;
        }
        __syncthreads();
        _Float16* xo = xh + ((size_t)n * HW_ + hw0) * 64;
#pragma unroll
        for (int i = 0; i < 4; ++i) {
            const int idx = i * 256 + threadIdx.x;
            const int c4  = idx & 15;               // c quad 0..15
            const int hr  = idx >> 4;               // 0..63
            h4 v;
            v.x = (_Float16)tile[hr][4 * c4 + 0];
            v.y = (_Float16)tile[hr][4 * c4 + 1];
            v.z = (_Float16)tile[hr][4 * c4 + 2];
            v.w = (_Float16)tile[hr][4 * c4 + 3];
            *(h4*)&xo[hr * 64 + 4 * c4] = v;        // 8B store, coalesced
        }
    } else {
        const int tid = (blockIdx.x - 1024) * 256 + threadIdx.x;  // 0..36863
        if (tid < COUT_ * KK_) {
            const int blk = tid >> 9;               // t*8 + kc*4 + mh (0..71)
            const int r   = tid & 511;
            const int l16 = r >> 5;
            const int ch  = r & 31;
            const int t   = blk >> 3;
            const int kc  = (blk >> 2) & 1;
            const int mh  = blk & 3;
            const int o   = mh * 16 + l16;
            const int c   = kc * 32 + ch;
            wA4[tid] = (_Float16)w[o * (C_ * K_) + c * K_ + t];
        }
    }
}

// ---------------------------------------------------------------------------
// Fused im2col+GEMM. Block = 256 thr / 4 waves, 64 px x 64 cout.
// Gather identity (R15-verified): lane (g=lane>>3, l8=lane&7) loads pixel
// pairs (wv*16+g, +8), channel octet 8*l8, 4 corners -> 8 h8 loads/tap.
// Pipeline per tap t (no vmcnt drain anywhere in the loop):
//   [A(t) 4 loads][ISSUE(t+2) 8 loads] -> compiler wait vmcnt(8) ->
//   MFMA(t) from Bt[t&1] -> FINISH(t+1) pk-fma+ds_write Bt[t&1^1] ->
//   lgkmcnt(0) -> raw s_barrier.
// ---------------------------------------------------------------------------
__global__ __launch_bounds__(256, 4) void dcn_fused(
    const _Float16* __restrict__ xh,   // (N, HW, C) fp16
    const float* __restrict__ offset,  // (N, 2*K, H, W)
    const float* __restrict__ mask,    // (N, K, H, W)
    const _Float16* __restrict__ wA4,  // repacked A, see prep
    const float* __restrict__ bias,
    float* __restrict__ out)           // (N, Cout, H, W)
{
    const int tid  = threadIdx.x;
    const int lane = tid & 63;
    const int wv   = tid >> 6;
    const int quad = lane >> 4;        // MFMA: k-octet selector
    const int l16  = lane & 15;        // MFMA: row/col lane
    const int g    = lane >> 3;        // gather: pixel-in-8
    const int l8   = lane & 7;         // gather: channel octet

    const int lb  = (blockIdx.x & 7) * 128 + (blockIdx.x >> 3);  // XCD swizzle
    const int pxb = lb * 64;                     // 64 | HW_: one image per block
    const int n   = pxb >> 14;
    const int hwb = pxb & (HW_ - 1);

    __shared__ _Float16 cwh[576][4];             // 4.6 KB fp16 bilinear weights
    __shared__ int      ci[576][4];              // 9.2 KB corner indices
    __shared__ _Float16 Bt[2][64][72];           // 18.4 KB [buf][px][c pad 72]

    // ---- phase 1: all coefs for this block's 64 px x 9 taps ----
#pragma unroll
    for (int r = 0; r < 3; ++r) {
        const int e = tid + 256 * r;
        if (e < 576) {
            const int p  = e / 9;                // magic-mul
            const int t  = e - p * 9;
            const int hw = hwb + p;
            const int ho = hw >> 7;
            const int wo = hw & (W_ - 1);
            const int ky = t / KW_;
            const int kx = t - ky * KW_;

            const float offy = offset[n * (2 * K_ * HW_) + (2 * t + 0) * HW_ + hw];
            const float offx = offset[n * (2 * K_ * HW_) + (2 * t + 1) * HW_ + hw];
            const float mval = mask[n * (K_ * HW_) + t * HW_ + hw];

            const float py = (float)(ho - 1 + ky) + offy;   // stride=1,pad=1,dil=1
            const float qx = (float)(wo - 1 + kx) + offx;
            const float y0f = floorf(py), x0f = floorf(qx);
            const float ly = py - y0f, lx = qx - x0f;
            const int y0 = (int)y0f, x0 = (int)x0f;
            const int y1 = y0 + 1,   x1 = x0 + 1;
            const bool vy0 = (y0 >= 0) & (y0 < H_);
            const bool vy1 = (y1 >= 0) & (y1 < H_);
            const bool vx0 = (x0 >= 0) & (x0 < W_);
            const bool vx1 = (x1 >= 0) & (x1 < W_);
            const int cy0 = min(max(y0, 0), H_ - 1);
            const int cy1 = min(max(y1, 0), H_ - 1);
            const int cx0 = min(max(x0, 0), W_ - 1);
            const int cx1 = min(max(x1, 0), W_ - 1);

            h4 q;
            q.x = (_Float16)((1.f - ly) * (1.f - lx) * mval * ((vy0 && vx0) ? 1.f : 0.f));
            q.y = (_Float16)((1.f - ly) * lx         * mval * ((vy0 && vx1) ? 1.f : 0.f));
            q.z = (_Float16)(ly         * (1.f - lx) * mval * ((vy1 && vx0) ? 1.f : 0.f));
            q.w = (_Float16)(ly         * lx         * mval * ((vy1 && vx1) ? 1.f : 0.f));
            *(h4*)&cwh[e][0] = q;
            int* qi = &ci[e][0];
            qi[0] = cy0 * W_ + cx0;
            qi[1] = cy0 * W_ + cx1;
            qi[2] = cy1 * W_ + cx0;
            qi[3] = cy1 * W_ + cx1;
        }
    }
    __syncthreads();                             // full drain once is fine here

    // gather base: this lane's channel octet (16B), fp16 units
    const _Float16* xb8 = xh + ((size_t)n * HW_) * 64 + 8 * l8;
    const int pg  = wv * 16 + g;                 // lane's pixel A (local)
    const int pg8 = pg + 8;                      // lane's pixel B (local)

    // wave's MFMA identity: cout half x pixel half
    const int mb   = (wv & 1) * 32;
    const int mhb  = (wv & 1) * 2;               // wave's mh' base in wA4 blocks
    const int pxwl = (wv >> 1) * 32;             // local pixel base for MFMA

    // A-frag lane base (R17-verified): frag (t,kc,mh') at block*512
    const _Float16* ab = wA4 + l16 * 32 + quad * 8;

    v4f acc[2][2];
#pragma unroll
    for (int mh = 0; mh < 2; ++mh)
#pragma unroll
        for (int nh = 0; nh < 2; ++nh)
            acc[mh][nh] = (v4f){0.f, 0.f, 0.f, 0.f};

    // register stages: [pixel A/B][corner 0..3], h8 each = 32 VGPR/stage
    h8 LA[2][4], LB[2][4];

    // issue tap t's 8 corner loads into stage R
#define ISSUE(t, R)                                                         \
    {                                                                       \
        const v4i oa = *(const v4i*)&ci[pg  * 9 + (t)][0];                  \
        const v4i ob = *(const v4i*)&ci[pg8 * 9 + (t)][0];                  \
        R[0][0] = *(const h8*)(xb8 + (size_t)oa.x * 64);                    \
        R[0][1] = *(const h8*)(xb8 + (size_t)oa.y * 64);                    \
        R[0][2] = *(const h8*)(xb8 + (size_t)oa.z * 64);                    \
        R[0][3] = *(const h8*)(xb8 + (size_t)oa.w * 64);                    \
        R[1][0] = *(const h8*)(xb8 + (size_t)ob.x * 64);                    \
        R[1][1] = *(const h8*)(xb8 + (size_t)ob.y * 64);                    \
        R[1][2] = *(const h8*)(xb8 + (size_t)ob.z * 64);                    \
        R[1][3] = *(const h8*)(xb8 + (size_t)ob.w * 64);                    \
    }

    // consume stage R for tap t: packed-fp16 bilinear + LDS write
#define FINISH(t, R, b)                                                     \
    {                                                                       \
        _Pragma("unroll")                                                   \
        for (int h = 0; h < 2; ++h) {                                       \
            const int p = wv * 16 + h * 8 + g;                              \
            const h4 f = *(const h4*)&cwh[p * 9 + (t)][0];                  \
            const h8 F0 = {f.x, f.x, f.x, f.x, f.x, f.x, f.x, f.x};         \
            const h8 F1 = {f.y, f.y, f.y, f.y, f.y, f.y, f.y, f.y};         \
            const h8 F2 = {f.z, f.z, f.z, f.z, f.z, f.z, f.z, f.z};         \
            const h8 F3 = {f.w, f.w, f.w, f.w, f.w, f.w, f.w, f.w};         \
            h8 rr = F0 * R[h][0];                                           \
            rr = __builtin_elementwise_fma(F1, R[h][1], rr);                \
            rr = __builtin_elementwise_fma(F2, R[h][2], rr);                \
            rr = __builtin_elementwise_fma(F3, R[h][3], rr);                \
            *(h8*)&Bt[b][p][8 * l8] = rr;                                   \
        }                                                                   \
    }

    // commit ds_writes + rendezvous WITHOUT draining vmcnt (the key change)
#define TAP_BARRIER()                                                       \
    __builtin_amdgcn_sched_barrier(0);                                      \
    asm volatile("s_waitcnt lgkmcnt(0)");                                   \
    __builtin_amdgcn_sched_barrier(0);                                      \
    __builtin_amdgcn_s_barrier();                                           \
    __builtin_amdgcn_sched_barrier(0);

    // ---- prologue: fill the 2-deep pipeline ----
    ISSUE(0, LA)
    ISSUE(1, LB)
    FINISH(0, LA, 0)
    TAP_BARRIER()

    // ---- main loop: 9 taps, counted-vmcnt pipeline across raw barriers ----
#pragma unroll
    for (int t = 0; t < K_; ++t) {
        const int buf = t & 1;

        // 1: A-frags FIRST (their dep-wait = vmcnt(8): retires ISSUE(t+1),
        //    which is one iteration old, and leaves ISSUE(t+2) in flight)
        h8 va[2][2];
#pragma unroll
        for (int kc = 0; kc < 2; ++kc)
#pragma unroll
            for (int mh = 0; mh < 2; ++mh)
                va[kc][mh] = *(const h8*)(ab
                    + (size_t)(t * 8 + kc * 4 + (mhb + mh)) * 512);
        __builtin_amdgcn_sched_barrier(0);

        // 2: prefetch B(t+2) into the stage just freed by FINISH(t+1 parity)
        if ((t & 1) == 0) {
            if (t + 2 < K_) ISSUE(t + 2, LA)
        } else {
            if (t + 2 < K_) ISSUE(t + 2, LB)
        }
        __builtin_amdgcn_sched_barrier(0);

        // 3: MFMA(t): B from Bt[buf] (written last iter, barrier'd)
#pragma unroll
        for (int kc = 0; kc < 2; ++kc) {
            h8 bfr[2];
#pragma unroll
            for (int nh = 0; nh < 2; ++nh)
                bfr[nh] = *(const h8*)&Bt[buf][pxwl + nh * 16 + l16][kc * 32 + quad * 8];
#pragma unroll
            for (int mh = 0; mh < 2; ++mh)
#pragma unroll
                for (int nh = 0; nh < 2; ++nh)
                    acc[mh][nh] = __builtin_amdgcn_mfma_f32_16x16x32_f16(
                        va[kc][mh], bfr[nh], acc[mh][nh], 0, 0, 0);
        }

        // 4: FINISH(t+1) -> Bt[buf^1] (stage regs already retired by step 1)
        if ((t & 1) == 0) {
            if (t + 1 < K_) FINISH(t + 1, LB, buf ^ 1)
        } else {
            if (t + 1 < K_) FINISH(t + 1, LA, buf ^ 1)
        }

        // 5: commit + barrier, vmcnt untouched
        TAP_BARRIER()
    }
#undef ISSUE
#undef FINISH
#undef TAP_BARRIER

    // D layout (R4-verified, dtype-independent): col = l16 (px), row = quad*4+r
    float* outb = out + n * (COUT_ * HW_);
#pragma unroll
    for (int mh = 0; mh < 2; ++mh)
#pragma unroll
        for (int nh = 0; nh < 2; ++nh)
#pragma unroll
            for (int r = 0; r < 4; ++r) {
                const int m = mb + mh * 16 + quad * 4 + r;
                outb[m * HW_ + hwb + pxwl + nh * 16 + l16] = acc[mh][nh][r] + bias[m];
            }
}

// ---------------------------------------------------------------------------
// Fallback (ws too small): R3-style direct fp32 kernel, no ws needed.
// ---------------------------------------------------------------------------
__global__ __launch_bounds__(256) void dcn_fallback(
    const float* __restrict__ x, const float* __restrict__ offset,
    const float* __restrict__ mask, const float* __restrict__ wptr,
    const float* __restrict__ bias, float* __restrict__ out)
{
    const int pix = blockIdx.x * 256 + threadIdx.x;
    const int n = pix >> 14, hw = pix & (HW_ - 1);
    const int ho = hw >> 7,  wo = hw & (W_ - 1);
    float acc[COUT_];
#pragma unroll
    for (int o = 0; o < COUT_; ++o) acc[o] = bias[o];
    const float* xn   = x + n * (C_ * HW_);
    const float* offn = offset + n * (2 * K_ * HW_) + hw;
    const float* mn   = mask + n * (K_ * HW_) + hw;
    for (int ct = 0; ct < C_; ct += 8) {
        for (int k = 0; k < K_; ++k) {
            const int ky = k / KW_, kx = k - ky * KW_;
            const float off_y = offn[(2 * k + 0) * HW_];
            const float off_x = offn[(2 * k + 1) * HW_];
            const float m = mn[k * HW_];
            const float py = (float)(ho - 1 + ky) + off_y;
            const float px = (float)(wo - 1 + kx) + off_x;
            const float y0f = floorf(py), x0f = floorf(px);
            const float ly = py - y0f, lx = px - x0f;
            const int y0 = (int)y0f, x0 = (int)x0f, y1 = y0 + 1, x1 = x0 + 1;
            const bool vy0 = (y0 >= 0) & (y0 < H_), vy1 = (y1 >= 0) & (y1 < H_);
            const bool vx0 = (x0 >= 0) & (x0 < W_), vx1 = (x1 >= 0) & (x1 < W_);
            const int cy0 = min(max(y0, 0), H_ - 1), cy1 = min(max(y1, 0), H_ - 1);
            const int cx0 = min(max(x0, 0), W_ - 1), cx1 = min(max(x1, 0), W_ - 1);
            const int i00 = cy0 * W_ + cx0, i01 = cy0 * W_ + cx1;
            const int i10 = cy1 * W_ + cx0, i11 = cy1 * W_ + cx1;
            const float f00 = (1.f - ly) * (1.f - lx) * m * ((vy0 && vx0) ? 1.f : 0.f);
            const float f01 = (1.f - ly) * lx * m * ((vy0 && vx1) ? 1.f : 0.f);
            const float f10 = ly * (1.f - lx) * m * ((vy1 && vx0) ? 1.f : 0.f);
            const float f11 = ly * lx * m * ((vy1 && vx1) ? 1.f : 0.f);
            for (int cc = 0; cc < 8; ++cc) {
                const int c = ct + cc;
                const float* xc = xn + c * HW_;
                const float val = fmaf(f00, xc[i00], fmaf(f01, xc[i01],
                                  fmaf(f10, xc[i10], f11 * xc[i11])));
#pragma unroll
                for (int o = 0; o < COUT_; ++o)
                    acc[o] = fmaf(wptr[o * (C_ * K_) + c * K_ + k], val, acc[o]);
            }
        }
    }
    float* outp = out + n * (COUT_ * HW_) + hw;
#pragma unroll
    for (int o = 0; o < COUT_; ++o) outp[o * HW_] = acc[o];
}

extern "C" void kernel_launch(void* const* d_in, const int* in_sizes, int n_in,
                              void* d_out, int out_size, void* d_ws, size_t ws_size,
                              hipStream_t stream) {
    const float* x      = (const float*)d_in[0];
    const float* offset = (const float*)d_in[1];
    const float* mask   = (const float*)d_in[2];
    const float* weight = (const float*)d_in[3];
    const float* bias   = (const float*)d_in[4];
    float* out = (float*)d_out;

    const size_t xh_bytes = (size_t)NPIX * C_ * sizeof(_Float16);  // 8.4 MB
    const size_t wA_bytes = (size_t)COUT_ * KK_ * sizeof(_Float16);// 73.7 KB

    if (ws_size >= xh_bytes + wA_bytes) {
        _Float16* xh  = (_Float16*)d_ws;
        _Float16* wA4 = (_Float16*)((char*)d_ws + xh_bytes);
        prep<<<1024 + 144, 256, 0, stream>>>(x, xh, weight, wA4);
        dcn_fused<<<NPIX / 64, 256, 0, stream>>>(xh, offset, mask, wA4, bias, out);
    } else {
        dcn_fallback<<<NPIX / 256, 256, 0, stream>>>(x, offset, mask, weight, bias, out);
    }
}

// Round 8
// 100.596 us; speedup vs baseline: 1.2964x; 1.0164x over previous
//
#include <hip/hip_runtime.h>

// DCNv2 forward = prep (weight repack + NHWC fp16 transpose) + FUSED
// im2col+GEMM. R20: FINISH-first iteration on the R19 skeleton.
//   iter t: FINISH(t) [consumes ISSUE(t), 2 iters old] -> va(t) ->
//           ISSUE(t+2) -> lgkmcnt(0)+s_barrier (NO vmcnt drain) ->
//           bfr ds_reads + 8x MFMA(t).
//   Gather slack: ISSUE(t)@t-2 .. FINISH(t)@t = 2 full iterations (R19's
//   FINISH-after-MFMA gave only ~1.15). Single barrier/iter still correct:
//   MFMA(t) reads Bt[t&1] behind bar@t; FINISH(t+1) writes Bt[t&1^1];
//   FINISH(t+2)'s reuse of Bt[t&1] is fenced by bar@t+1.
//   Coef phase now COALESCED: thread = pixel (tid&63), loop taps ->
//   27 x 256B-coalesced loads/block (was 1728 scattered dwords).
// R19 measured: total 102.2, fused ~33 us, drain removal verified.
#define N_    4
#define C_    64
#define H_    128
#define W_    128
#define KW_   3
#define K_    9
#define COUT_ 64
#define HW_   (H_ * W_)     // 16384
#define NPIX  (N_ * HW_)    // 65536
#define KK_   (C_ * K_)     // 576

typedef _Float16 h4 __attribute__((ext_vector_type(4)));
typedef _Float16 h8 __attribute__((ext_vector_type(8)));   // 16B, 4 VGPRs
typedef float v4f __attribute__((ext_vector_type(4)));     // MFMA C/D
typedef int   v4i __attribute__((ext_vector_type(4)));

// ---------------------------------------------------------------------------
// prep: one dispatch doing both prologue jobs (unchanged from R19, verified).
//   blocks 0..1023  : NCHW fp32 -> NHWC fp16 transpose xh[n][hw][c]
//   blocks 1024..1167: wA4 repack:
//     wA4[(t*8+kc*4+mh)*512 + l16*32 + ch] = fp16(w[mh*16+l16][kc*32+ch][t])
// ---------------------------------------------------------------------------
__global__ __launch_bounds__(256) void prep(
    const float* __restrict__ x, _Float16* __restrict__ xh,
    const float* __restrict__ w, _Float16* __restrict__ wA4)
{
    if (blockIdx.x < 1024) {
        const int n   = blockIdx.x >> 8;            // 4 images x 256 hw-tiles
        const int hw0 = (blockIdx.x & 255) * 64;

        __shared__ float tile[64][65];              // [hw][c], pad
        const float* xb = x + n * (C_ * HW_);
#pragma unroll
        for (int i = 0; i < 4; ++i) {
            const int idx = i * 256 + threadIdx.x;  // 0..1023
            const int q   = idx & 15;               // hw quad 0..15
            const int c   = idx >> 4;               // 0..63
            const v4f v = *(const v4f*)&xb[c * HW_ + hw0 + 4 * q];
            tile[4 * q + 0][c] = v.x;
            tile[4 * q + 1][c] = v.y;
            tile[4 * q + 2][c] = v.z;
            tile[4 * q + 3][c] = v.w;
        }
        __syncthreads();
        _Float16* xo = xh + ((size_t)n * HW_ + hw0) * 64;
#pragma unroll
        for (int i = 0; i < 4; ++i) {
            const int idx = i * 256 + threadIdx.x;
            const int c4  = idx & 15;               // c quad 0..15
            const int hr  = idx >> 4;               // 0..63
            h4 v;
            v.x = (_Float16)tile[hr][4 * c4 + 0];
            v.y = (_Float16)tile[hr][4 * c4 + 1];
            v.z = (_Float16)tile[hr][4 * c4 + 2];
            v.w = (_Float16)tile[hr][4 * c4 + 3];
            *(h4*)&xo[hr * 64 + 4 * c4] = v;        // 8B store, coalesced
        }
    } else {
        const int tid = (blockIdx.x - 1024) * 256 + threadIdx.x;  // 0..36863
        if (tid < COUT_ * KK_) {
            const int blk = tid >> 9;               // t*8 + kc*4 + mh (0..71)
            const int r   = tid & 511;
            const int l16 = r >> 5;
            const int ch  = r & 31;
            const int t   = blk >> 3;
            const int kc  = (blk >> 2) & 1;
            const int mh  = blk & 3;
            const int o   = mh * 16 + l16;
            const int c   = kc * 32 + ch;
            wA4[tid] = (_Float16)w[o * (C_ * K_) + c * K_ + t];
        }
    }
}

// ---------------------------------------------------------------------------
// Fused im2col+GEMM. Block = 256 thr / 4 waves, 64 px x 64 cout.
// Gather (R15-verified): lane (g=lane>>3, l8=lane&7) loads pixels
// (wv*16+g, +8), channel octet 8*l8, 4 corners -> 8 h8 loads/tap,
// 8 lanes cover one 128B row (coalesced).
// ---------------------------------------------------------------------------
__global__ __launch_bounds__(256, 4) void dcn_fused(
    const _Float16* __restrict__ xh,   // (N, HW, C) fp16
    const float* __restrict__ offset,  // (N, 2*K, H, W)
    const float* __restrict__ mask,    // (N, K, H, W)
    const _Float16* __restrict__ wA4,  // repacked A, see prep
    const float* __restrict__ bias,
    float* __restrict__ out)           // (N, Cout, H, W)
{
    const int tid  = threadIdx.x;
    const int lane = tid & 63;
    const int wv   = tid >> 6;
    const int quad = lane >> 4;        // MFMA: k-octet selector
    const int l16  = lane & 15;        // MFMA: row/col lane
    const int g    = lane >> 3;        // gather: pixel-in-8
    const int l8   = lane & 7;         // gather: channel octet

    const int lb  = (blockIdx.x & 7) * 128 + (blockIdx.x >> 3);  // XCD swizzle
    const int pxb = lb * 64;                     // 64 | HW_: one image per block
    const int n   = pxb >> 14;
    const int hwb = pxb & (HW_ - 1);

    __shared__ _Float16 cwh[576][4];             // 4.6 KB fp16 bilinear weights
    __shared__ int      ci[576][4];              // 9.2 KB corner indices
    __shared__ _Float16 Bt[2][64][72];           // 18.4 KB [buf][px][c pad 72]

    // ---- phase 1 (COALESCED): thread = pixel tid&63, taps {q, q+4, q+8} ----
    {
        const int p  = tid & 63;                 // block-local pixel
        const int q  = tid >> 6;                 // 0..3
        const int hw = hwb + p;
        const int ho = hw >> 7;
        const int wo = hw & (W_ - 1);
        const float* offp = offset + n * (2 * K_ * HW_) + hw;
        const float* mp   = mask   + n * (K_ * HW_) + hw;
#pragma unroll
        for (int j = 0; j < 3; ++j) {
            const int t = q + 4 * j;
            if (t < K_) {                        // q=0 covers t=8
                const int ky = t / KW_;
                const int kx = t - ky * KW_;
                // lanes have consecutive hw -> 256B coalesced per load
                const float offy = offp[(2 * t + 0) * HW_];
                const float offx = offp[(2 * t + 1) * HW_];
                const float mval = mp[t * HW_];

                const float py = (float)(ho - 1 + ky) + offy;  // s=1,p=1,d=1
                const float qx = (float)(wo - 1 + kx) + offx;
                const float y0f = floorf(py), x0f = floorf(qx);
                const float ly = py - y0f, lx = qx - x0f;
                const int y0 = (int)y0f, x0 = (int)x0f;
                const int y1 = y0 + 1,   x1 = x0 + 1;
                const bool vy0 = (y0 >= 0) & (y0 < H_);
                const bool vy1 = (y1 >= 0) & (y1 < H_);
                const bool vx0 = (x0 >= 0) & (x0 < W_);
                const bool vx1 = (x1 >= 0) & (x1 < W_);
                const int cy0 = min(max(y0, 0), H_ - 1);
                const int cy1 = min(max(y1, 0), H_ - 1);
                const int cx0 = min(max(x0, 0), W_ - 1);
                const int cx1 = min(max(x1, 0), W_ - 1);

                const int e = p * 9 + t;
                h4 qq;
                qq.x = (_Float16)((1.f - ly) * (1.f - lx) * mval * ((vy0 && vx0) ? 1.f : 0.f));
                qq.y = (_Float16)((1.f - ly) * lx         * mval * ((vy0 && vx1) ? 1.f : 0.f));
                qq.z = (_Float16)(ly         * (1.f - lx) * mval * ((vy1 && vx0) ? 1.f : 0.f));
                qq.w = (_Float16)(ly         * lx         * mval * ((vy1 && vx1) ? 1.f : 0.f));
                *(h4*)&cwh[e][0] = qq;
                int* qi = &ci[e][0];
                qi[0] = cy0 * W_ + cx0;
                qi[1] = cy0 * W_ + cx1;
                qi[2] = cy1 * W_ + cx0;
                qi[3] = cy1 * W_ + cx1;
            }
        }
    }
    __syncthreads();                             // full drain once is fine here

    // gather base: this lane's channel octet (16B), fp16 units
    const _Float16* xb8 = xh + ((size_t)n * HW_) * 64 + 8 * l8;
    const int pg  = wv * 16 + g;                 // lane's pixel A (local)
    const int pg8 = pg + 8;                      // lane's pixel B (local)

    // wave's MFMA identity: cout half x pixel half
    const int mb   = (wv & 1) * 32;
    const int mhb  = (wv & 1) * 2;               // wave's mh' base in wA4 blocks
    const int pxwl = (wv >> 1) * 32;             // local pixel base for MFMA

    // A-frag lane base (R17-verified layout)
    const _Float16* ab = wA4 + l16 * 32 + quad * 8;

    v4f acc[2][2];
#pragma unroll
    for (int mh = 0; mh < 2; ++mh)
#pragma unroll
        for (int nh = 0; nh < 2; ++nh)
            acc[mh][nh] = (v4f){0.f, 0.f, 0.f, 0.f};

    // register stages: [pixel A/B][corner 0..3], h8 each = 32 VGPR/stage
    h8 LA[2][4], LB[2][4];

#define ISSUE(t, R)                                                         \
    {                                                                       \
        const v4i oa = *(const v4i*)&ci[pg  * 9 + (t)][0];                  \
        const v4i ob = *(const v4i*)&ci[pg8 * 9 + (t)][0];                  \
        R[0][0] = *(const h8*)(xb8 + (size_t)oa.x * 64);                    \
        R[0][1] = *(const h8*)(xb8 + (size_t)oa.y * 64);                    \
        R[0][2] = *(const h8*)(xb8 + (size_t)oa.z * 64);                    \
        R[0][3] = *(const h8*)(xb8 + (size_t)oa.w * 64);                    \
        R[1][0] = *(const h8*)(xb8 + (size_t)ob.x * 64);                    \
        R[1][1] = *(const h8*)(xb8 + (size_t)ob.y * 64);                    \
        R[1][2] = *(const h8*)(xb8 + (size_t)ob.z * 64);                    \
        R[1][3] = *(const h8*)(xb8 + (size_t)ob.w * 64);                    \
    }

#define FINISH(t, R, b)                                                     \
    {                                                                       \
        _Pragma("unroll")                                                   \
        for (int h = 0; h < 2; ++h) {                                       \
            const int p = wv * 16 + h * 8 + g;                              \
            const h4 f = *(const h4*)&cwh[p * 9 + (t)][0];                  \
            const h8 F0 = {f.x, f.x, f.x, f.x, f.x, f.x, f.x, f.x};         \
            const h8 F1 = {f.y, f.y, f.y, f.y, f.y, f.y, f.y, f.y};         \
            const h8 F2 = {f.z, f.z, f.z, f.z, f.z, f.z, f.z, f.z};         \
            const h8 F3 = {f.w, f.w, f.w, f.w, f.w, f.w, f.w, f.w};         \
            h8 rr = F0 * R[h][0];                                           \
            rr = __builtin_elementwise_fma(F1, R[h][1], rr);                \
            rr = __builtin_elementwise_fma(F2, R[h][2], rr);                \
            rr = __builtin_elementwise_fma(F3, R[h][3], rr);                \
            *(h8*)&Bt[b][p][8 * l8] = rr;                                   \
        }                                                                   \
    }

    // commit ds_writes + rendezvous WITHOUT draining vmcnt (R19-verified)
#define TAP_BARRIER()                                                       \
    __builtin_amdgcn_sched_barrier(0);                                      \
    asm volatile("s_waitcnt lgkmcnt(0)");                                   \
    __builtin_amdgcn_sched_barrier(0);                                      \
    __builtin_amdgcn_s_barrier();                                           \
    __builtin_amdgcn_sched_barrier(0);

    // ---- prologue: 2 gather taps in flight ----
    ISSUE(0, LA)
    ISSUE(1, LB)
    __builtin_amdgcn_sched_barrier(0);

    // ---- main loop: FINISH(t) -> va(t) -> ISSUE(t+2) -> bar -> MFMA(t) ----
#pragma unroll
    for (int t = 0; t < K_; ++t) {
        const int buf = t & 1;

        // 1: FINISH(t): consumes ISSUE(t) (2 iterations old -> wait cheap),
        //    writes Bt[buf]
        if ((t & 1) == 0) {
            FINISH(t, LA, buf)
        } else {
            FINISH(t, LB, buf)
        }
        __builtin_amdgcn_sched_barrier(0);

        // 2: A-frags for tap t (small, L1/L2-hot)
        h8 va[2][2];
#pragma unroll
        for (int kc = 0; kc < 2; ++kc)
#pragma unroll
            for (int mh = 0; mh < 2; ++mh)
                va[kc][mh] = *(const h8*)(ab
                    + (size_t)(t * 8 + kc * 4 + (mhb + mh)) * 512);
        __builtin_amdgcn_sched_barrier(0);

        // 3: refill freed stage with tap t+2 (consumed at FINISH(t+2):
        //    2 full iterations of flight time)
        if ((t & 1) == 0) {
            if (t + 2 < K_) ISSUE(t + 2, LA)
        } else {
            if (t + 2 < K_) ISSUE(t + 2, LB)
        }

        // 4: commit + barrier, vmcnt untouched
        TAP_BARRIER()

        // 5: MFMA(t): B from Bt[buf] (written this iter, behind barrier)
        __builtin_amdgcn_s_setprio(1);
#pragma unroll
        for (int kc = 0; kc < 2; ++kc) {
            h8 bfr[2];
#pragma unroll
            for (int nh = 0; nh < 2; ++nh)
                bfr[nh] = *(const h8*)&Bt[buf][pxwl + nh * 16 + l16][kc * 32 + quad * 8];
#pragma unroll
            for (int mh = 0; mh < 2; ++mh)
#pragma unroll
                for (int nh = 0; nh < 2; ++nh)
                    acc[mh][nh] = __builtin_amdgcn_mfma_f32_16x16x32_f16(
                        va[kc][mh], bfr[nh], acc[mh][nh], 0, 0, 0);
        }
        __builtin_amdgcn_s_setprio(0);
        __builtin_amdgcn_sched_barrier(0);
    }
#undef ISSUE
#undef FINISH
#undef TAP_BARRIER

    // D layout (R4-verified, dtype-independent): col = l16 (px), row = quad*4+r
    float* outb = out + n * (COUT_ * HW_);
#pragma unroll
    for (int mh = 0; mh < 2; ++mh)
#pragma unroll
        for (int nh = 0; nh < 2; ++nh)
#pragma unroll
            for (int r = 0; r < 4; ++r) {
                const int m = mb + mh * 16 + quad * 4 + r;
                outb[m * HW_ + hwb + pxwl + nh * 16 + l16] = acc[mh][nh][r] + bias[m];
            }
}

// ---------------------------------------------------------------------------
// Fallback (ws too small): R3-style direct fp32 kernel, no ws needed.
// ---------------------------------------------------------------------------
__global__ __launch_bounds__(256) void dcn_fallback(
    const float* __restrict__ x, const float* __restrict__ offset,
    const float* __restrict__ mask, const float* __restrict__ wptr,
    const float* __restrict__ bias, float* __restrict__ out)
{
    const int pix = blockIdx.x * 256 + threadIdx.x;
    const int n = pix >> 14, hw = pix & (HW_ - 1);
    const int ho = hw >> 7,  wo = hw & (W_ - 1);
    float acc[COUT_];
#pragma unroll
    for (int o = 0; o < COUT_; ++o) acc[o] = bias[o];
    const float* xn   = x + n * (C_ * HW_);
    const float* offn = offset + n * (2 * K_ * HW_) + hw;
    const float* mn   = mask + n * (K_ * HW_) + hw;
    for (int ct = 0; ct < C_; ct += 8) {
        for (int k = 0; k < K_; ++k) {
            const int ky = k / KW_, kx = k - ky * KW_;
            const float off_y = offn[(2 * k + 0) * HW_];
            const float off_x = offn[(2 * k + 1) * HW_];
            const float m = mn[k * HW_];
            const float py = (float)(ho - 1 + ky) + off_y;
            const float px = (float)(wo - 1 + kx) + off_x;
            const float y0f = floorf(py), x0f = floorf(px);
            const float ly = py - y0f, lx = px - x0f;
            const int y0 = (int)y0f, x0 = (int)x0f, y1 = y0 + 1, x1 = x0 + 1;
            const bool vy0 = (y0 >= 0) & (y0 < H_), vy1 = (y1 >= 0) & (y1 < H_);
            const bool vx0 = (x0 >= 0) & (x0 < W_), vx1 = (x1 >= 0) & (x1 < W_);
            const int cy0 = min(max(y0, 0), H_ - 1), cy1 = min(max(y1, 0), H_ - 1);
            const int cx0 = min(max(x0, 0), W_ - 1), cx1 = min(max(x1, 0), W_ - 1);
            const int i00 = cy0 * W_ + cx0, i01 = cy0 * W_ + cx1;
            const int i10 = cy1 * W_ + cx0, i11 = cy1 * W_ + cx1;
            const float f00 = (1.f - ly) * (1.f - lx) * m * ((vy0 && vx0) ? 1.f : 0.f);
            const float f01 = (1.f - ly) * lx * m * ((vy0 && vx1) ? 1.f : 0.f);
            const float f10 = ly * (1.f - lx) * m * ((vy1 && vx0) ? 1.f : 0.f);
            const float f11 = ly * lx * m * ((vy1 && vx1) ? 1.f : 0.f);
            for (int cc = 0; cc < 8; ++cc) {
                const int c = ct + cc;
                const float* xc = xn + c * HW_;
                const float val = fmaf(f00, xc[i00], fmaf(f01, xc[i01],
                                  fmaf(f10, xc[i10], f11 * xc[i11])));
#pragma unroll
                for (int o = 0; o < COUT_; ++o)
                    acc[o] = fmaf(wptr[o * (C_ * K_) + c * K_ + k], val, acc[o]);
            }
        }
    }
    float* outp = out + n * (COUT_ * HW_) + hw;
#pragma unroll
    for (int o = 0; o < COUT_; ++o) outp[o * HW_] = acc[o];
}

extern "C" void kernel_launch(void* const* d_in, const int* in_sizes, int n_in,
                              void* d_out, int out_size, void* d_ws, size_t ws_size,
                              hipStream_t stream) {
    const float* x      = (const float*)d_in[0];
    const float* offset = (const float*)d_in[1];
    const float* mask   = (const float*)d_in[2];
    const float* weight = (const float*)d_in[3];
    const float* bias   = (const float*)d_in[4];
    float* out = (float*)d_out;

    const size_t xh_bytes = (size_t)NPIX * C_ * sizeof(_Float16);  // 8.4 MB
    const size_t wA_bytes = (size_t)COUT_ * KK_ * sizeof(_Float16);// 73.7 KB

    if (ws_size >= xh_bytes + wA_bytes) {
        _Float16* xh  = (_Float16*)d_ws;
        _Float16* wA4 = (_Float16*)((char*)d_ws + xh_bytes);
        prep<<<1024 + 144, 256, 0, stream>>>(x, xh, weight, wA4);
        dcn_fused<<<NPIX / 64, 256, 0, stream>>>(xh, offset, mask, wA4, bias, out);
    } else {
        dcn_fallback<<<NPIX / 256, 256, 0, stream>>>(x, offset, mask, weight, bias, out);
    }
}